// Round 1
// baseline (346.217 us; speedup 1.0000x reference)
//
#include <hip/hip_runtime.h>
#include <cstdint>
#include <cstddef>

// Problem constants
#define B_   4
#define S_   4096
#define H_   1024
#define NH_  16
#define D_   64
#define M_TOT (B_ * S_)    // 16384 rows of hidden
#define K_TOT H_           // 1024 reduction dim
#define N_TOT (3 * H_)     // 3072 = concat(Q,K,V) output cols
#define SCALE_ 0.125f      // 1/sqrt(64)
#define NCH 4              // chunks for global-attention online softmax
#define CH (S_ / NCH)      // 1024 positions per chunk

typedef __bf16 bf16x8 __attribute__((ext_vector_type(8)));
typedef float  f32x4  __attribute__((ext_vector_type(4)));

__device__ __forceinline__ unsigned short f2b(float x) {
    unsigned int u = __float_as_uint(x);
    u += 0x7FFFu + ((u >> 16) & 1u);          // round-to-nearest-even
    return (unsigned short)(u >> 16);
}
__device__ __forceinline__ float b2f(unsigned int u) {   // u = bf16 bits in low 16
    return __uint_as_float(u << 16);
}

// ---------------------------------------------------------------- converts
__global__ __launch_bounds__(256) void cvt_x(const float* __restrict__ src,
                                             unsigned short* __restrict__ dst, int n4) {
    int i = blockIdx.x * blockDim.x + threadIdx.x;
    int stride = gridDim.x * blockDim.x;
    for (; i < n4; i += stride) {
        float4 v = ((const float4*)src)[i];
        ushort4 o;
        o.x = f2b(v.x); o.y = f2b(v.y); o.z = f2b(v.z); o.w = f2b(v.w);
        ((ushort4*)dst)[i] = o;
    }
}

// grid (H*H/4/256, 3): converts Wq,Wk,Wv into one contiguous N_TOT x K bf16 matrix
__global__ __launch_bounds__(256) void cvt_w(const float* __restrict__ w0,
                                             const float* __restrict__ w1,
                                             const float* __restrict__ w2,
                                             unsigned short* __restrict__ dst) {
    const int per4 = H_ * H_ / 4;
    int i = blockIdx.x * blockDim.x + threadIdx.x;   // exact cover, no bound check
    const float* s = (blockIdx.y == 0) ? w0 : (blockIdx.y == 1 ? w1 : w2);
    float4 v = ((const float4*)s)[i];
    ushort4 o;
    o.x = f2b(v.x); o.y = f2b(v.y); o.z = f2b(v.z); o.w = f2b(v.w);
    ((ushort4*)(dst + (size_t)blockIdx.y * H_ * H_))[i] = o;
}

// ---------------------------------------------------------------- QKV GEMM
// C[m,n] = sum_k A[m,k]*W[n,k] (+bias[n]) ; A: M x K bf16, W: N x K bf16, C: M x N bf16
// 128x128 tile, BK=32, 256 threads = 4 waves in 2x2, each wave 64x64 via 4x4 MFMA 16x16x32.
__global__ __launch_bounds__(256) void gemm_qkv(const unsigned short* __restrict__ A,
                                                const unsigned short* __restrict__ W,
                                                const float* __restrict__ bq,
                                                const float* __restrict__ bk,
                                                const float* __restrict__ bv,
                                                unsigned short* __restrict__ C) {
    __shared__ unsigned short As[128 * 32] __attribute__((aligned(16)));
    __shared__ unsigned short Bs[128 * 32] __attribute__((aligned(16)));
    const int tid  = threadIdx.x;
    const int wid  = tid >> 6;
    const int lane = tid & 63;
    const int wm = wid >> 1, wn = wid & 1;
    const int m0 = blockIdx.y * 128;
    const int n0 = blockIdx.x * 128;

    f32x4 acc[4][4];
#pragma unroll
    for (int i = 0; i < 4; i++)
#pragma unroll
        for (int j = 0; j < 4; j++) acc[i][j] = (f32x4){0.f, 0.f, 0.f, 0.f};

    const int lrow = lane >> 2;        // 0..15 : row within 16-row slab
    const int lcol = (lane & 3) * 8;   // 0,8,16,24 : k-element offset (16B chunk)

    for (int k0 = 0; k0 < K_TOT; k0 += 32) {
        // stage 128x32 A and B slabs; each wave copies 2x16 rows of each (1KB/inst)
#pragma unroll
        for (int i = 0; i < 2; i++) {
            const int r0 = wid * 32 + i * 16;
            const unsigned short* ga = A + (size_t)(m0 + r0 + lrow) * K_TOT + k0 + lcol;
            __builtin_amdgcn_global_load_lds(
                (const __attribute__((address_space(1))) void*)ga,
                (__attribute__((address_space(3))) void*)&As[r0 * 32], 16, 0, 0);
            const unsigned short* gb = W + (size_t)(n0 + r0 + lrow) * K_TOT + k0 + lcol;
            __builtin_amdgcn_global_load_lds(
                (const __attribute__((address_space(1))) void*)gb,
                (__attribute__((address_space(3))) void*)&Bs[r0 * 32], 16, 0, 0);
        }
        __syncthreads();   // drains vmcnt -> staged data visible

        bf16x8 af[4], bfv[4];
#pragma unroll
        for (int mi = 0; mi < 4; mi++)
            af[mi] = *(const bf16x8*)&As[(wm * 64 + mi * 16 + (lane & 15)) * 32 + (lane >> 4) * 8];
#pragma unroll
        for (int ni = 0; ni < 4; ni++)
            bfv[ni] = *(const bf16x8*)&Bs[(wn * 64 + ni * 16 + (lane & 15)) * 32 + (lane >> 4) * 8];
#pragma unroll
        for (int mi = 0; mi < 4; mi++)
#pragma unroll
            for (int ni = 0; ni < 4; ni++)
                acc[mi][ni] = __builtin_amdgcn_mfma_f32_16x16x32_bf16(af[mi], bfv[ni], acc[mi][ni], 0, 0, 0);
        __syncthreads();   // protect LDS before next stage overwrites
    }

    // epilogue: C/D layout col=lane&15, row=(lane>>4)*4+i
    const int col_l = lane & 15;
    const int quad  = lane >> 4;
#pragma unroll
    for (int mi = 0; mi < 4; mi++) {
#pragma unroll
        for (int ni = 0; ni < 4; ni++) {
            const int gc = n0 + wn * 64 + ni * 16 + col_l;
            const float bias = (gc < H_) ? bq[gc] : (gc < 2 * H_ ? bk[gc - H_] : bv[gc - 2 * H_]);
#pragma unroll
            for (int i = 0; i < 4; i++) {
                const int gr = m0 + wm * 64 + mi * 16 + quad * 4 + i;
                C[(size_t)gr * N_TOT + gc] = f2b(acc[mi][ni][i] + bias);
            }
        }
    }
}

// ------------------------------------------------- global attention (s=0 query)
// grid (B*NH, NCH), 256 thr. Online-softmax partials per chunk of 1024 keys.
__global__ __launch_bounds__(256) void gattn_part(const unsigned short* __restrict__ QKV,
                                                  const float* __restrict__ mask,
                                                  float* __restrict__ Pm,
                                                  float* __restrict__ Pl,
                                                  float* __restrict__ Po) {
    const int bh = blockIdx.x;
    const int b = bh >> 4, h = bh & 15;
    const int chunk = blockIdx.y;
    const int tid = threadIdx.x;
    const int w = tid >> 6, lane = tid & 63;

    __shared__ float gq_sh[D_];
    __shared__ float pr[CH];        // unnormalized probabilities
    __shared__ float red[8];
    __shared__ float osum[4][D_];

    const unsigned short* gqp = QKV + (size_t)(b * S_) * N_TOT + h * D_;
    if (tid < D_) gq_sh[tid] = b2f(gqp[tid]);
    __syncthreads();

    const int s0 = chunk * CH;
    float sreg[4];
    float smax = -1e30f;
    for (int j = 0; j < 4; j++) {
        const int sl = tid + j * 256;
        const int s  = s0 + sl;
        const uint4* kp4 = (const uint4*)(QKV + (size_t)(b * S_ + s) * N_TOT + H_ + h * D_);
        float acc = 0.f;
#pragma unroll
        for (int c = 0; c < 8; c++) {
            uint4 r = kp4[c];
            acc += b2f(r.x & 0xffffu) * gq_sh[c * 8 + 0];
            acc += b2f(r.x >> 16)     * gq_sh[c * 8 + 1];
            acc += b2f(r.y & 0xffffu) * gq_sh[c * 8 + 2];
            acc += b2f(r.y >> 16)     * gq_sh[c * 8 + 3];
            acc += b2f(r.z & 0xffffu) * gq_sh[c * 8 + 4];
            acc += b2f(r.z >> 16)     * gq_sh[c * 8 + 5];
            acc += b2f(r.w & 0xffffu) * gq_sh[c * 8 + 6];
            acc += b2f(r.w >> 16)     * gq_sh[c * 8 + 7];
        }
        const float sv = acc * SCALE_ + mask[b * S_ + s];
        sreg[j] = sv;
        smax = fmaxf(smax, sv);
    }
    // block max
    float wmax = smax;
#pragma unroll
    for (int m = 32; m >= 1; m >>= 1) wmax = fmaxf(wmax, __shfl_xor(wmax, m, 64));
    if (lane == 0) red[w] = wmax;
    __syncthreads();
    const float bmax = fmaxf(fmaxf(red[0], red[1]), fmaxf(red[2], red[3]));

    float lsum = 0.f;
    for (int j = 0; j < 4; j++) {
        const int sl = tid + j * 256;
        const float p = __expf(sreg[j] - bmax);
        pr[sl] = p;
        lsum += p;
    }
    float wsum = lsum;
#pragma unroll
    for (int m = 32; m >= 1; m >>= 1) wsum += __shfl_xor(wsum, m, 64);
    if (lane == 0) red[4 + w] = wsum;
    __syncthreads();   // also publishes pr[] for phase 2
    const float bsum = red[4] + red[5] + red[6] + red[7];

    // o[d] = sum_s p[s] * v[s][d]; wave w covers its 256-s subrange
    float o = 0.f;
    const int sbase = s0 + w * 256;
    for (int i = 0; i < 256; i++) {
        const int s = sbase + i;
        const float vv = b2f((unsigned int)QKV[(size_t)(b * S_ + s) * N_TOT + 2 * H_ + h * D_ + lane]);
        o += pr[w * 256 + i] * vv;
    }
    osum[w][lane] = o;
    __syncthreads();
    if (tid < D_) {
        const float ot = osum[0][tid] + osum[1][tid] + osum[2][tid] + osum[3][tid];
        Po[(size_t)(bh * NCH + chunk) * D_ + tid] = ot;
        if (tid == 0) {
            Pm[bh * NCH + chunk] = bmax;
            Pl[bh * NCH + chunk] = bsum;
        }
    }
}

// combine 4 chunk partials -> ctx row s=0
__global__ __launch_bounds__(64) void gattn_comb(const float* __restrict__ Pm,
                                                 const float* __restrict__ Pl,
                                                 const float* __restrict__ Po,
                                                 float* __restrict__ out) {
    const int bh = blockIdx.x, d = threadIdx.x;
    const int b = bh >> 4, h = bh & 15;
    const float m0 = Pm[bh * 4 + 0], m1 = Pm[bh * 4 + 1], m2 = Pm[bh * 4 + 2], m3 = Pm[bh * 4 + 3];
    const float ms = fmaxf(fmaxf(m0, m1), fmaxf(m2, m3));
    const float e0 = __expf(m0 - ms), e1 = __expf(m1 - ms), e2 = __expf(m2 - ms), e3 = __expf(m3 - ms);
    const float z = Pl[bh * 4 + 0] * e0 + Pl[bh * 4 + 1] * e1 + Pl[bh * 4 + 2] * e2 + Pl[bh * 4 + 3] * e3;
    const float o = Po[(size_t)(bh * 4 + 0) * D_ + d] * e0 + Po[(size_t)(bh * 4 + 1) * D_ + d] * e1 +
                    Po[(size_t)(bh * 4 + 2) * D_ + d] * e2 + Po[(size_t)(bh * 4 + 3) * D_ + d] * e3;
    out[(size_t)b * S_ * H_ + (size_t)h * D_ + d] = o / z;
}

// ------------------------------------------------- local attention, s in [1,S)
// grid (B*NH, 1024), 256 thr = 4 waves, one wave per sequence position
__global__ __launch_bounds__(256) void lattn(const unsigned short* __restrict__ QKV,
                                             float* __restrict__ ctx,
                                             float* __restrict__ lat) {
    const int bh = blockIdx.x;
    const int b = bh >> 4, h = bh & 15;
    const int w = threadIdx.x >> 6, lane = threadIdx.x & 63;
    const int s = 1 + blockIdx.y * 4 + w;
    if (s >= S_) return;

    const size_t rowS = (size_t)(b * S_ + s) * N_TOT + h * D_;
    const size_t row0 = (size_t)(b * S_) * N_TOT + h * D_;
    const float qd  = b2f((unsigned int)QKV[rowS + lane]);
    const float kd  = b2f((unsigned int)QKV[rowS + H_ + lane]);
    const float k0d = b2f((unsigned int)QKV[row0 + H_ + lane]);

    float ps = qd * kd, pg = qd * k0d;
#pragma unroll
    for (int m = 32; m >= 1; m >>= 1) {
        ps += __shfl_xor(ps, m, 64);
        pg += __shfl_xor(pg, m, 64);
    }
    ps *= SCALE_; pg *= SCALE_;
    const float mx = fmaxf(ps, pg);
    const float e0 = __expf(ps - mx), e1 = __expf(pg - mx);
    const float z = e0 + e1;
    const float p0 = e0 / z, p1 = e1 / z;

    const float vd  = b2f((unsigned int)QKV[rowS + 2 * H_ + lane]);
    const float v0d = b2f((unsigned int)QKV[row0 + 2 * H_ + lane]);
    ctx[(size_t)b * (S_ * H_) + (size_t)s * H_ + h * D_ + lane] = p0 * vd + p1 * v0d;
    if (lane == 0) {
        const size_t li = ((size_t)bh * (S_ - 1) + (s - 1)) * 2;
        lat[li]     = p0;
        lat[li + 1] = p1;
    }
}

// ---------------------------------------------------------------- launcher
extern "C" void kernel_launch(void* const* d_in, const int* in_sizes, int n_in,
                              void* d_out, int out_size, void* d_ws, size_t ws_size,
                              hipStream_t stream) {
    const float* hs   = (const float*)d_in[0];
    const float* mask = (const float*)d_in[1];
    const float* Wq   = (const float*)d_in[2];
    const float* bq   = (const float*)d_in[3];
    const float* Wk   = (const float*)d_in[4];
    const float* bk   = (const float*)d_in[5];
    const float* Wv   = (const float*)d_in[6];
    const float* bv   = (const float*)d_in[7];

    float* out = (float*)d_out;                       // (B,S,H) fp32
    float* lat = out + (size_t)B_ * S_ * H_;          // (B,NH,S-1,1,2) fp32

    char* ws = (char*)d_ws;
    const size_t offXb  = 0;
    const size_t offWb  = offXb  + (size_t)M_TOT * K_TOT * 2;
    const size_t offQKV = offWb  + (size_t)3 * H_ * H_ * 2;
    const size_t offPm  = offQKV + (size_t)M_TOT * N_TOT * 2;
    const size_t offPl  = offPm  + (size_t)B_ * NH_ * NCH * 4;
    const size_t offPo  = offPl  + (size_t)B_ * NH_ * NCH * 4;

    unsigned short* Xb  = (unsigned short*)(ws + offXb);
    unsigned short* Wb  = (unsigned short*)(ws + offWb);
    unsigned short* QKV = (unsigned short*)(ws + offQKV);
    float* Pm = (float*)(ws + offPm);
    float* Pl = (float*)(ws + offPl);
    float* Po = (float*)(ws + offPo);

    hipLaunchKernelGGL(cvt_x, dim3(4096), dim3(256), 0, stream, hs, Xb, M_TOT * K_TOT / 4);
    hipLaunchKernelGGL(cvt_w, dim3(H_ * H_ / 4 / 256, 3), dim3(256), 0, stream, Wq, Wk, Wv, Wb);
    hipLaunchKernelGGL(gemm_qkv, dim3(N_TOT / 128, M_TOT / 128), dim3(256), 0, stream,
                       Xb, Wb, bq, bk, bv, QKV);
    hipLaunchKernelGGL(gattn_part, dim3(B_ * NH_, NCH), dim3(256), 0, stream, QKV, mask, Pm, Pl, Po);
    hipLaunchKernelGGL(gattn_comb, dim3(B_ * NH_), dim3(64), 0, stream, Pm, Pl, Po, out);
    hipLaunchKernelGGL(lattn, dim3(B_ * NH_, 1024), dim3(256), 0, stream, QKV, out, lat);
}

// Round 2
// 308.819 us; speedup vs baseline: 1.1211x; 1.1211x over previous
//
#include <hip/hip_runtime.h>
#include <cstdint>
#include <cstddef>

// Problem constants
#define B_   4
#define S_   4096
#define H_   1024
#define NH_  16
#define D_   64
#define M_TOT (B_ * S_)    // 16384 rows of hidden
#define K_TOT H_           // 1024 reduction dim
#define N_TOT (3 * H_)     // 3072 = concat(Q,K,V) output cols
#define SCALE_ 0.125f      // 1/sqrt(64)
#define NCH 16             // chunks for global-attention online softmax
#define CH (S_ / NCH)      // 256 positions per chunk

typedef __bf16 bf16x8 __attribute__((ext_vector_type(8)));
typedef float  f32x4  __attribute__((ext_vector_type(4)));

__device__ __forceinline__ unsigned short f2b(float x) {
    unsigned int u = __float_as_uint(x);
    u += 0x7FFFu + ((u >> 16) & 1u);          // round-to-nearest-even
    return (unsigned short)(u >> 16);
}
__device__ __forceinline__ float b2f(unsigned int u) {   // u = bf16 bits in low 16
    return __uint_as_float(u << 16);
}
__device__ __forceinline__ void unp8(uint4 u, float* f) {
    f[0] = b2f(u.x & 0xffffu); f[1] = b2f(u.x >> 16);
    f[2] = b2f(u.y & 0xffffu); f[3] = b2f(u.y >> 16);
    f[4] = b2f(u.z & 0xffffu); f[5] = b2f(u.z >> 16);
    f[6] = b2f(u.w & 0xffffu); f[7] = b2f(u.w >> 16);
}

// ------------------------------------------------- fused fp32->bf16 converts
// covers X (2^22 float4 groups) then Wq|Wk|Wv (3 x 2^18 groups). Exact grid.
__global__ __launch_bounds__(256) void cvt_all(const float* __restrict__ hs,
                                               const float* __restrict__ wq,
                                               const float* __restrict__ wk,
                                               const float* __restrict__ wv,
                                               unsigned short* __restrict__ Xb,
                                               unsigned short* __restrict__ Wb) {
    const int i = blockIdx.x * 256 + threadIdx.x;
    const int X4 = M_TOT * K_TOT / 4;          // 4194304 = 2^22
    float4 v;
    ushort4 o;
    if (i < X4) {
        v = ((const float4*)hs)[i];
        o.x = f2b(v.x); o.y = f2b(v.y); o.z = f2b(v.z); o.w = f2b(v.w);
        ((ushort4*)Xb)[i] = o;
    } else {
        const int j = i - X4;
        const int w = j >> 18;                 // H*H/4 = 2^18
        const int off = j & 0x3ffff;
        const float* s = (w == 0) ? wq : (w == 1 ? wk : wv);
        v = ((const float4*)s)[off];
        o.x = f2b(v.x); o.y = f2b(v.y); o.z = f2b(v.z); o.w = f2b(v.w);
        ((ushort4*)(Wb + (size_t)w * H_ * H_))[off] = o;
    }
}

// ---------------------------------------------------------------- QKV GEMM
// C[m,n] = sum_k A[m,k]*W[n,k] (+bias[n]) ; A: M x K bf16, W: N x K bf16, C: M x N bf16
// 128x128 tile, BK=32, 256 threads = 4 waves in 2x2, each wave 64x64 via 4x4 MFMA 16x16x32.
// UNCHANGED from round 1 (known-good, 145 us, at the m97-structure plateau).
__global__ __launch_bounds__(256) void gemm_qkv(const unsigned short* __restrict__ A,
                                                const unsigned short* __restrict__ W,
                                                const float* __restrict__ bq,
                                                const float* __restrict__ bk,
                                                const float* __restrict__ bv,
                                                unsigned short* __restrict__ C) {
    __shared__ unsigned short As[128 * 32] __attribute__((aligned(16)));
    __shared__ unsigned short Bs[128 * 32] __attribute__((aligned(16)));
    const int tid  = threadIdx.x;
    const int wid  = tid >> 6;
    const int lane = tid & 63;
    const int wm = wid >> 1, wn = wid & 1;
    const int m0 = blockIdx.y * 128;
    const int n0 = blockIdx.x * 128;

    f32x4 acc[4][4];
#pragma unroll
    for (int i = 0; i < 4; i++)
#pragma unroll
        for (int j = 0; j < 4; j++) acc[i][j] = (f32x4){0.f, 0.f, 0.f, 0.f};

    const int lrow = lane >> 2;        // 0..15 : row within 16-row slab
    const int lcol = (lane & 3) * 8;   // 0,8,16,24 : k-element offset (16B chunk)

    for (int k0 = 0; k0 < K_TOT; k0 += 32) {
#pragma unroll
        for (int i = 0; i < 2; i++) {
            const int r0 = wid * 32 + i * 16;
            const unsigned short* ga = A + (size_t)(m0 + r0 + lrow) * K_TOT + k0 + lcol;
            __builtin_amdgcn_global_load_lds(
                (const __attribute__((address_space(1))) void*)ga,
                (__attribute__((address_space(3))) void*)&As[r0 * 32], 16, 0, 0);
            const unsigned short* gb = W + (size_t)(n0 + r0 + lrow) * K_TOT + k0 + lcol;
            __builtin_amdgcn_global_load_lds(
                (const __attribute__((address_space(1))) void*)gb,
                (__attribute__((address_space(3))) void*)&Bs[r0 * 32], 16, 0, 0);
        }
        __syncthreads();

        bf16x8 af[4], bfv[4];
#pragma unroll
        for (int mi = 0; mi < 4; mi++)
            af[mi] = *(const bf16x8*)&As[(wm * 64 + mi * 16 + (lane & 15)) * 32 + (lane >> 4) * 8];
#pragma unroll
        for (int ni = 0; ni < 4; ni++)
            bfv[ni] = *(const bf16x8*)&Bs[(wn * 64 + ni * 16 + (lane & 15)) * 32 + (lane >> 4) * 8];
#pragma unroll
        for (int mi = 0; mi < 4; mi++)
#pragma unroll
            for (int ni = 0; ni < 4; ni++)
                acc[mi][ni] = __builtin_amdgcn_mfma_f32_16x16x32_bf16(af[mi], bfv[ni], acc[mi][ni], 0, 0, 0);
        __syncthreads();
    }

    const int col_l = lane & 15;
    const int quad  = lane >> 4;
#pragma unroll
    for (int mi = 0; mi < 4; mi++) {
#pragma unroll
        for (int ni = 0; ni < 4; ni++) {
            const int gc = n0 + wn * 64 + ni * 16 + col_l;
            const float bias = (gc < H_) ? bq[gc] : (gc < 2 * H_ ? bk[gc - H_] : bv[gc - 2 * H_]);
#pragma unroll
            for (int i = 0; i < 4; i++) {
                const int gr = m0 + wm * 64 + mi * 16 + quad * 4 + i;
                C[(size_t)gr * N_TOT + gc] = f2b(acc[mi][ni][i] + bias);
            }
        }
    }
}

// ------------------------------------------------- global attention (s=0 query)
// grid (B*NH, NCH=16), 256 thr. One key position per thread in phase 1;
// 64-iteration PV loop per wave in phase 2. 1024 blocks -> 4 blocks/CU.
__global__ __launch_bounds__(256) void gattn_part(const unsigned short* __restrict__ QKV,
                                                  const float* __restrict__ mask,
                                                  float* __restrict__ Pm,
                                                  float* __restrict__ Pl,
                                                  float* __restrict__ Po) {
    const int bh = blockIdx.x;
    const int b = bh >> 4, h = bh & 15;
    const int chunk = blockIdx.y;
    const int tid = threadIdx.x;
    const int w = tid >> 6, lane = tid & 63;

    __shared__ float gq_sh[D_];
    __shared__ float pr[CH];
    __shared__ float red[8];
    __shared__ float osum[4][D_];

    const unsigned short* gqp = QKV + (size_t)(b * S_) * N_TOT + h * D_;
    if (tid < D_) gq_sh[tid] = b2f(gqp[tid]);
    __syncthreads();

    const int s0 = chunk * CH;
    const int s  = s0 + tid;
    const uint4* kp4 = (const uint4*)(QKV + (size_t)(b * S_ + s) * N_TOT + H_ + h * D_);
    float acc = 0.f;
#pragma unroll
    for (int c = 0; c < 8; c++) {
        uint4 r = kp4[c];
        acc += b2f(r.x & 0xffffu) * gq_sh[c * 8 + 0];
        acc += b2f(r.x >> 16)     * gq_sh[c * 8 + 1];
        acc += b2f(r.y & 0xffffu) * gq_sh[c * 8 + 2];
        acc += b2f(r.y >> 16)     * gq_sh[c * 8 + 3];
        acc += b2f(r.z & 0xffffu) * gq_sh[c * 8 + 4];
        acc += b2f(r.z >> 16)     * gq_sh[c * 8 + 5];
        acc += b2f(r.w & 0xffffu) * gq_sh[c * 8 + 6];
        acc += b2f(r.w >> 16)     * gq_sh[c * 8 + 7];
    }
    const float sv = acc * SCALE_ + mask[b * S_ + s];

    float wmax = sv;
#pragma unroll
    for (int m = 32; m >= 1; m >>= 1) wmax = fmaxf(wmax, __shfl_xor(wmax, m, 64));
    if (lane == 0) red[w] = wmax;
    __syncthreads();
    const float bmax = fmaxf(fmaxf(red[0], red[1]), fmaxf(red[2], red[3]));

    const float p = __expf(sv - bmax);
    pr[tid] = p;
    float wsum = p;
#pragma unroll
    for (int m = 32; m >= 1; m >>= 1) wsum += __shfl_xor(wsum, m, 64);
    if (lane == 0) red[4 + w] = wsum;
    __syncthreads();   // publishes pr[] for phase 2
    const float bsum = red[4] + red[5] + red[6] + red[7];

    // o[d] = sum_s p[s] * v[s][d]; wave w covers 64 consecutive s
    float o = 0.f;
    const int sbase = s0 + w * 64;
#pragma unroll 8
    for (int i = 0; i < 64; i++) {
        const int si = sbase + i;
        const float vv = b2f((unsigned int)QKV[(size_t)(b * S_ + si) * N_TOT + 2 * H_ + h * D_ + lane]);
        o += pr[w * 64 + i] * vv;
    }
    osum[w][lane] = o;
    __syncthreads();
    if (tid < D_) {
        const float ot = osum[0][tid] + osum[1][tid] + osum[2][tid] + osum[3][tid];
        Po[(size_t)(bh * NCH + chunk) * D_ + tid] = ot;
        if (tid == 0) {
            Pm[bh * NCH + chunk] = bmax;
            Pl[bh * NCH + chunk] = bsum;
        }
    }
}

// combine NCH chunk partials -> ctx row s=0
__global__ __launch_bounds__(64) void gattn_comb(const float* __restrict__ Pm,
                                                 const float* __restrict__ Pl,
                                                 const float* __restrict__ Po,
                                                 float* __restrict__ out) {
    const int bh = blockIdx.x, d = threadIdx.x;
    const int b = bh >> 4, h = bh & 15;
    float ms = -1e30f;
#pragma unroll
    for (int c = 0; c < NCH; c++) ms = fmaxf(ms, Pm[bh * NCH + c]);
    float z = 0.f, o = 0.f;
#pragma unroll
    for (int c = 0; c < NCH; c++) {
        const float e = __expf(Pm[bh * NCH + c] - ms);
        z += Pl[bh * NCH + c] * e;
        o += Po[(size_t)(bh * NCH + c) * D_ + d] * e;
    }
    out[(size_t)b * S_ * H_ + (size_t)h * D_ + d] = o / z;
}

// ------------------------------------------------- local attention, s in [1,S)
// grid (B*NH, 128), 256 thr = 4 waves; wave handles 8 s-positions with 8 lanes
// each (lane covers 8 d-elements via one uint4 = 16 B load).
__global__ __launch_bounds__(256) void lattn(const unsigned short* __restrict__ QKV,
                                             float* __restrict__ ctx,
                                             float* __restrict__ lat) {
    const int bh = blockIdx.x;
    const int b = bh >> 4, h = bh & 15;
    const int w = threadIdx.x >> 6, lane = threadIdx.x & 63;
    const int g = lane >> 3;     // s-subgroup within wave
    const int l = lane & 7;      // d-octet index
    const int s = 1 + blockIdx.y * 32 + w * 8 + g;
    if (s >= S_) return;         // only the very last 8-lane group; no later barriers

    const size_t rowS = (size_t)(b * S_ + s) * N_TOT + h * D_ + l * 8;
    const size_t row0 = (size_t)(b * S_) * N_TOT + h * D_ + l * 8;

    uint4 qu  = *(const uint4*)(QKV + rowS);
    uint4 ku  = *(const uint4*)(QKV + rowS + H_);
    uint4 k0u = *(const uint4*)(QKV + row0 + H_);
    float qf[8], kf[8], k0f[8];
    unp8(qu, qf); unp8(ku, kf); unp8(k0u, k0f);

    float ps = 0.f, pg = 0.f;
#pragma unroll
    for (int i = 0; i < 8; i++) { ps += qf[i] * kf[i]; pg += qf[i] * k0f[i]; }
#pragma unroll
    for (int m = 1; m < 8; m <<= 1) {   // reduce within the 8-lane d-group
        ps += __shfl_xor(ps, m, 64);
        pg += __shfl_xor(pg, m, 64);
    }
    ps *= SCALE_; pg *= SCALE_;
    const float mx = fmaxf(ps, pg);
    const float e0 = __expf(ps - mx), e1 = __expf(pg - mx);
    const float z = e0 + e1;
    const float p0 = e0 / z, p1 = e1 / z;

    uint4 vu  = *(const uint4*)(QKV + rowS + 2 * H_);
    uint4 v0u = *(const uint4*)(QKV + row0 + 2 * H_);
    float vf[8], v0f[8];
    unp8(vu, vf); unp8(v0u, v0f);

    float* cp = ctx + (size_t)b * (S_ * H_) + (size_t)s * H_ + h * D_ + l * 8;
    float4 o0, o1;
    o0.x = p0 * vf[0] + p1 * v0f[0];
    o0.y = p0 * vf[1] + p1 * v0f[1];
    o0.z = p0 * vf[2] + p1 * v0f[2];
    o0.w = p0 * vf[3] + p1 * v0f[3];
    o1.x = p0 * vf[4] + p1 * v0f[4];
    o1.y = p0 * vf[5] + p1 * v0f[5];
    o1.z = p0 * vf[6] + p1 * v0f[6];
    o1.w = p0 * vf[7] + p1 * v0f[7];
    ((float4*)cp)[0] = o0;
    ((float4*)cp)[1] = o1;

    if (l == 0) {
        float2 lp; lp.x = p0; lp.y = p1;
        ((float2*)(lat + ((size_t)bh * (S_ - 1) + (s - 1)) * 2))[0] = lp;
    }
}

// ---------------------------------------------------------------- launcher
extern "C" void kernel_launch(void* const* d_in, const int* in_sizes, int n_in,
                              void* d_out, int out_size, void* d_ws, size_t ws_size,
                              hipStream_t stream) {
    const float* hs   = (const float*)d_in[0];
    const float* mask = (const float*)d_in[1];
    const float* Wq   = (const float*)d_in[2];
    const float* bq   = (const float*)d_in[3];
    const float* Wk   = (const float*)d_in[4];
    const float* bk   = (const float*)d_in[5];
    const float* Wv   = (const float*)d_in[6];
    const float* bv   = (const float*)d_in[7];

    float* out = (float*)d_out;                       // (B,S,H) fp32
    float* lat = out + (size_t)B_ * S_ * H_;          // (B,NH,S-1,1,2) fp32

    char* ws = (char*)d_ws;
    const size_t offXb  = 0;
    const size_t offWb  = offXb  + (size_t)M_TOT * K_TOT * 2;
    const size_t offQKV = offWb  + (size_t)3 * H_ * H_ * 2;
    const size_t offPm  = offQKV + (size_t)M_TOT * N_TOT * 2;
    const size_t offPl  = offPm  + (size_t)B_ * NH_ * NCH * 4;
    const size_t offPo  = offPl  + (size_t)B_ * NH_ * NCH * 4;

    unsigned short* Xb  = (unsigned short*)(ws + offXb);
    unsigned short* Wb  = (unsigned short*)(ws + offWb);
    unsigned short* QKV = (unsigned short*)(ws + offQKV);
    float* Pm = (float*)(ws + offPm);
    float* Pl = (float*)(ws + offPl);
    float* Po = (float*)(ws + offPo);

    const int total4 = M_TOT * K_TOT / 4 + 3 * H_ * H_ / 4;   // 4980736, /256 exact
    hipLaunchKernelGGL(cvt_all, dim3(total4 / 256), dim3(256), 0, stream,
                       hs, Wq, Wk, Wv, Xb, Wb);
    hipLaunchKernelGGL(gemm_qkv, dim3(N_TOT / 128, M_TOT / 128), dim3(256), 0, stream,
                       Xb, Wb, bq, bk, bv, QKV);
    hipLaunchKernelGGL(gattn_part, dim3(B_ * NH_, NCH), dim3(256), 0, stream, QKV, mask, Pm, Pl, Po);
    hipLaunchKernelGGL(gattn_comb, dim3(B_ * NH_), dim3(64), 0, stream, Pm, Pl, Po, out);
    hipLaunchKernelGGL(lattn, dim3(B_ * NH_, 128), dim3(256), 0, stream, QKV, out, lat);
}

// Round 3
// 305.868 us; speedup vs baseline: 1.1319x; 1.0096x over previous
//
#include <hip/hip_runtime.h>
#include <cstdint>
#include <cstddef>

// Problem constants
#define B_   4
#define S_   4096
#define H_   1024
#define NH_  16
#define D_   64
#define M_TOT (B_ * S_)    // 16384 rows of hidden
#define K_TOT H_           // 1024 reduction dim
#define N_TOT (3 * H_)     // 3072 = concat(Q,K,V) output cols
#define SCALE_ 0.125f      // 1/sqrt(64)
#define NCH 16             // chunks for global-attention online softmax
#define CH (S_ / NCH)      // 256 positions per chunk

typedef __bf16 bf16x8 __attribute__((ext_vector_type(8)));
typedef float  f32x4  __attribute__((ext_vector_type(4)));

__device__ __forceinline__ unsigned short f2b(float x) {
    unsigned int u = __float_as_uint(x);
    u += 0x7FFFu + ((u >> 16) & 1u);          // round-to-nearest-even
    return (unsigned short)(u >> 16);
}
__device__ __forceinline__ float b2f(unsigned int u) {   // u = bf16 bits in low 16
    return __uint_as_float(u << 16);
}
__device__ __forceinline__ void unp8(uint4 u, float* f) {
    f[0] = b2f(u.x & 0xffffu); f[1] = b2f(u.x >> 16);
    f[2] = b2f(u.y & 0xffffu); f[3] = b2f(u.y >> 16);
    f[4] = b2f(u.z & 0xffffu); f[5] = b2f(u.z >> 16);
    f[6] = b2f(u.w & 0xffffu); f[7] = b2f(u.w >> 16);
}
__device__ __forceinline__ unsigned int pack2(float lo, float hi) {
    return (unsigned int)f2b(lo) | ((unsigned int)f2b(hi) << 16);
}

// ------------------------------------------------- fused fp32->bf16 converts
// 8 floats per thread: 2 float4 loads -> 1 uint4 (8 bf16) store.
// covers X (2^21 groups) then Wq|Wk|Wv (3 x 2^17 groups). Exact grid.
__global__ __launch_bounds__(256) void cvt_all(const float* __restrict__ hs,
                                               const float* __restrict__ wq,
                                               const float* __restrict__ wk,
                                               const float* __restrict__ wv,
                                               unsigned short* __restrict__ Xb,
                                               unsigned short* __restrict__ Wb) {
    const int i = blockIdx.x * 256 + threadIdx.x;
    const int X8 = M_TOT * K_TOT / 8;          // 2097152 = 2^21
    const float4* sp;
    uint4* dp;
    int off;
    if (i < X8) {
        sp = (const float4*)hs;
        dp = (uint4*)Xb;
        off = i;
    } else {
        const int j = i - X8;
        const int w = j >> 17;                 // H*H/8 = 2^17
        off = j & 0x1ffff;
        sp = (const float4*)((w == 0) ? wq : (w == 1 ? wk : wv));
        dp = (uint4*)(Wb + (size_t)w * H_ * H_);
    }
    const float4 v0 = sp[off * 2];
    const float4 v1 = sp[off * 2 + 1];
    uint4 o;
    o.x = pack2(v0.x, v0.y);
    o.y = pack2(v0.z, v0.w);
    o.z = pack2(v1.x, v1.y);
    o.w = pack2(v1.z, v1.w);
    dp[off] = o;
}

// ---------------------------------------------------------------- QKV GEMM
// C[m,n] = sum_k A[m,k]*W[n,k] (+bias[n]) ; A: M x K bf16, W: N x K bf16, C: M x N bf16
// 128x128 tile, BK=32, 256 threads = 4 waves in 2x2, each wave 64x64 via 4x4 MFMA 16x16x32.
// Round 3: XOR chunk swizzle (chunk' = chunk ^ ((row>>1)&3)) applied on the staging
// global k-offset (LDS dst is HW-forced to lane*16) and on the ds_read slot.
// Breaks the 8-way bank conflict of the un-swizzled layout (rows 0..7 now start at
// bank-words {0,16,4,20,8,24,12,28} -> full 32-bank coverage, 2-way = free).
__global__ __launch_bounds__(256) void gemm_qkv(const unsigned short* __restrict__ A,
                                                const unsigned short* __restrict__ W,
                                                const float* __restrict__ bq,
                                                const float* __restrict__ bk,
                                                const float* __restrict__ bv,
                                                unsigned short* __restrict__ C) {
    __shared__ unsigned short As[128 * 32] __attribute__((aligned(16)));
    __shared__ unsigned short Bs[128 * 32] __attribute__((aligned(16)));
    const int tid  = threadIdx.x;
    const int wid  = tid >> 6;
    const int lane = tid & 63;
    const int wm = wid >> 1, wn = wid & 1;
    const int m0 = blockIdx.y * 128;
    const int n0 = blockIdx.x * 128;

    f32x4 acc[4][4];
#pragma unroll
    for (int i = 0; i < 4; i++)
#pragma unroll
        for (int j = 0; j < 4; j++) acc[i][j] = (f32x4){0.f, 0.f, 0.f, 0.f};

    const int lrow = lane >> 2;                                 // 0..15 : row within 16-row slab
    const int lcol = (((lane & 3) ^ ((lrow >> 1) & 3))) * 8;    // swizzled k-chunk offset

    // fragment-read swizzle: slot = chunk ^ ((row>>1)&3); row bits 1,2 come from lane&15
    const int rl    = lane & 15;
    const int slot8 = ((lane >> 4) ^ ((rl >> 1) & 3)) * 8;      // element offset of 16B slot

    for (int k0 = 0; k0 < K_TOT; k0 += 32) {
#pragma unroll
        for (int i = 0; i < 2; i++) {
            const int r0 = wid * 32 + i * 16;
            const unsigned short* ga = A + (size_t)(m0 + r0 + lrow) * K_TOT + k0 + lcol;
            __builtin_amdgcn_global_load_lds(
                (const __attribute__((address_space(1))) void*)ga,
                (__attribute__((address_space(3))) void*)&As[r0 * 32], 16, 0, 0);
            const unsigned short* gb = W + (size_t)(n0 + r0 + lrow) * K_TOT + k0 + lcol;
            __builtin_amdgcn_global_load_lds(
                (const __attribute__((address_space(1))) void*)gb,
                (__attribute__((address_space(3))) void*)&Bs[r0 * 32], 16, 0, 0);
        }
        __syncthreads();

        bf16x8 af[4], bfv[4];
#pragma unroll
        for (int mi = 0; mi < 4; mi++)
            af[mi] = *(const bf16x8*)&As[(wm * 64 + mi * 16 + rl) * 32 + slot8];
#pragma unroll
        for (int ni = 0; ni < 4; ni++)
            bfv[ni] = *(const bf16x8*)&Bs[(wn * 64 + ni * 16 + rl) * 32 + slot8];
#pragma unroll
        for (int mi = 0; mi < 4; mi++)
#pragma unroll
            for (int ni = 0; ni < 4; ni++)
                acc[mi][ni] = __builtin_amdgcn_mfma_f32_16x16x32_bf16(af[mi], bfv[ni], acc[mi][ni], 0, 0, 0);
        __syncthreads();
    }

    const int col_l = lane & 15;
    const int quad  = lane >> 4;
#pragma unroll
    for (int mi = 0; mi < 4; mi++) {
#pragma unroll
        for (int ni = 0; ni < 4; ni++) {
            const int gc = n0 + wn * 64 + ni * 16 + col_l;
            const float bias = (gc < H_) ? bq[gc] : (gc < 2 * H_ ? bk[gc - H_] : bv[gc - 2 * H_]);
#pragma unroll
            for (int i = 0; i < 4; i++) {
                const int gr = m0 + wm * 64 + mi * 16 + quad * 4 + i;
                C[(size_t)gr * N_TOT + gc] = f2b(acc[mi][ni][i] + bias);
            }
        }
    }
}

// ------------------------------------------------- global attention (s=0 query)
// grid (B*NH, NCH=16), 256 thr. One key position per thread in phase 1;
// 64-iteration PV loop per wave in phase 2. 1024 blocks -> 4 blocks/CU.
__global__ __launch_bounds__(256) void gattn_part(const unsigned short* __restrict__ QKV,
                                                  const float* __restrict__ mask,
                                                  float* __restrict__ Pm,
                                                  float* __restrict__ Pl,
                                                  float* __restrict__ Po) {
    const int bh = blockIdx.x;
    const int b = bh >> 4, h = bh & 15;
    const int chunk = blockIdx.y;
    const int tid = threadIdx.x;
    const int w = tid >> 6, lane = tid & 63;

    __shared__ float gq_sh[D_];
    __shared__ float pr[CH];
    __shared__ float red[8];
    __shared__ float osum[4][D_];

    const unsigned short* gqp = QKV + (size_t)(b * S_) * N_TOT + h * D_;
    if (tid < D_) gq_sh[tid] = b2f(gqp[tid]);
    __syncthreads();

    const int s0 = chunk * CH;
    const int s  = s0 + tid;
    const uint4* kp4 = (const uint4*)(QKV + (size_t)(b * S_ + s) * N_TOT + H_ + h * D_);
    float acc = 0.f;
#pragma unroll
    for (int c = 0; c < 8; c++) {
        uint4 r = kp4[c];
        acc += b2f(r.x & 0xffffu) * gq_sh[c * 8 + 0];
        acc += b2f(r.x >> 16)     * gq_sh[c * 8 + 1];
        acc += b2f(r.y & 0xffffu) * gq_sh[c * 8 + 2];
        acc += b2f(r.y >> 16)     * gq_sh[c * 8 + 3];
        acc += b2f(r.z & 0xffffu) * gq_sh[c * 8 + 4];
        acc += b2f(r.z >> 16)     * gq_sh[c * 8 + 5];
        acc += b2f(r.w & 0xffffu) * gq_sh[c * 8 + 6];
        acc += b2f(r.w >> 16)     * gq_sh[c * 8 + 7];
    }
    const float sv = acc * SCALE_ + mask[b * S_ + s];

    float wmax = sv;
#pragma unroll
    for (int m = 32; m >= 1; m >>= 1) wmax = fmaxf(wmax, __shfl_xor(wmax, m, 64));
    if (lane == 0) red[w] = wmax;
    __syncthreads();
    const float bmax = fmaxf(fmaxf(red[0], red[1]), fmaxf(red[2], red[3]));

    const float p = __expf(sv - bmax);
    pr[tid] = p;
    float wsum = p;
#pragma unroll
    for (int m = 32; m >= 1; m >>= 1) wsum += __shfl_xor(wsum, m, 64);
    if (lane == 0) red[4 + w] = wsum;
    __syncthreads();   // publishes pr[] for phase 2
    const float bsum = red[4] + red[5] + red[6] + red[7];

    // o[d] = sum_s p[s] * v[s][d]; wave w covers 64 consecutive s
    float o = 0.f;
    const int sbase = s0 + w * 64;
#pragma unroll 8
    for (int i = 0; i < 64; i++) {
        const int si = sbase + i;
        const float vv = b2f((unsigned int)QKV[(size_t)(b * S_ + si) * N_TOT + 2 * H_ + h * D_ + lane]);
        o += pr[w * 64 + i] * vv;
    }
    osum[w][lane] = o;
    __syncthreads();
    if (tid < D_) {
        const float ot = osum[0][tid] + osum[1][tid] + osum[2][tid] + osum[3][tid];
        Po[(size_t)(bh * NCH + chunk) * D_ + tid] = ot;
        if (tid == 0) {
            Pm[bh * NCH + chunk] = bmax;
            Pl[bh * NCH + chunk] = bsum;
        }
    }
}

// ------------------------------------------------- local attention + combine
// grid (B*NH, 129), 256 thr. y<128: 4 waves; wave handles 8 s-positions with
// 8 lanes each (lane covers 8 d via one uint4 = 16B load). y==128: combine the
// NCH global-attention partials into ctx row s=0 (threads 0..63).
__global__ __launch_bounds__(256) void lattn(const unsigned short* __restrict__ QKV,
                                             float* __restrict__ ctx,
                                             float* __restrict__ lat,
                                             const float* __restrict__ Pm,
                                             const float* __restrict__ Pl,
                                             const float* __restrict__ Po) {
    const int bh = blockIdx.x;
    const int b = bh >> 4, h = bh & 15;

    if (blockIdx.y == 128) {
        const int d = threadIdx.x;
        if (d < D_) {
            float ms = -1e30f;
#pragma unroll
            for (int c = 0; c < NCH; c++) ms = fmaxf(ms, Pm[bh * NCH + c]);
            float z = 0.f, o = 0.f;
#pragma unroll
            for (int c = 0; c < NCH; c++) {
                const float e = __expf(Pm[bh * NCH + c] - ms);
                z += Pl[bh * NCH + c] * e;
                o += Po[(size_t)(bh * NCH + c) * D_ + d] * e;
            }
            ctx[(size_t)b * S_ * H_ + (size_t)h * D_ + d] = o / z;
        }
        return;
    }

    const int w = threadIdx.x >> 6, lane = threadIdx.x & 63;
    const int g = lane >> 3;     // s-subgroup within wave
    const int l = lane & 7;      // d-octet index
    const int s = 1 + blockIdx.y * 32 + w * 8 + g;
    if (s >= S_) return;         // only the very last 8-lane group; no later barriers

    const size_t rowS = (size_t)(b * S_ + s) * N_TOT + h * D_ + l * 8;
    const size_t row0 = (size_t)(b * S_) * N_TOT + h * D_ + l * 8;

    uint4 qu  = *(const uint4*)(QKV + rowS);
    uint4 ku  = *(const uint4*)(QKV + rowS + H_);
    uint4 k0u = *(const uint4*)(QKV + row0 + H_);
    float qf[8], kf[8], k0f[8];
    unp8(qu, qf); unp8(ku, kf); unp8(k0u, k0f);

    float ps = 0.f, pg = 0.f;
#pragma unroll
    for (int i = 0; i < 8; i++) { ps += qf[i] * kf[i]; pg += qf[i] * k0f[i]; }
#pragma unroll
    for (int m = 1; m < 8; m <<= 1) {   // reduce within the 8-lane d-group
        ps += __shfl_xor(ps, m, 64);
        pg += __shfl_xor(pg, m, 64);
    }
    ps *= SCALE_; pg *= SCALE_;
    const float mx = fmaxf(ps, pg);
    const float e0 = __expf(ps - mx), e1 = __expf(pg - mx);
    const float z = e0 + e1;
    const float p0 = e0 / z, p1 = e1 / z;

    uint4 vu  = *(const uint4*)(QKV + rowS + 2 * H_);
    uint4 v0u = *(const uint4*)(QKV + row0 + 2 * H_);
    float vf[8], v0f[8];
    unp8(vu, vf); unp8(v0u, v0f);

    float* cp = ctx + (size_t)b * (S_ * H_) + (size_t)s * H_ + h * D_ + l * 8;
    float4 o0, o1;
    o0.x = p0 * vf[0] + p1 * v0f[0];
    o0.y = p0 * vf[1] + p1 * v0f[1];
    o0.z = p0 * vf[2] + p1 * v0f[2];
    o0.w = p0 * vf[3] + p1 * v0f[3];
    o1.x = p0 * vf[4] + p1 * v0f[4];
    o1.y = p0 * vf[5] + p1 * v0f[5];
    o1.z = p0 * vf[6] + p1 * v0f[6];
    o1.w = p0 * vf[7] + p1 * v0f[7];
    ((float4*)cp)[0] = o0;
    ((float4*)cp)[1] = o1;

    if (l == 0) {
        float2 lp; lp.x = p0; lp.y = p1;
        ((float2*)(lat + ((size_t)bh * (S_ - 1) + (s - 1)) * 2))[0] = lp;
    }
}

// ---------------------------------------------------------------- launcher
extern "C" void kernel_launch(void* const* d_in, const int* in_sizes, int n_in,
                              void* d_out, int out_size, void* d_ws, size_t ws_size,
                              hipStream_t stream) {
    const float* hs   = (const float*)d_in[0];
    const float* mask = (const float*)d_in[1];
    const float* Wq   = (const float*)d_in[2];
    const float* bq   = (const float*)d_in[3];
    const float* Wk   = (const float*)d_in[4];
    const float* bk   = (const float*)d_in[5];
    const float* Wv   = (const float*)d_in[6];
    const float* bv   = (const float*)d_in[7];

    float* out = (float*)d_out;                       // (B,S,H) fp32
    float* lat = out + (size_t)B_ * S_ * H_;          // (B,NH,S-1,1,2) fp32

    char* ws = (char*)d_ws;
    const size_t offXb  = 0;
    const size_t offWb  = offXb  + (size_t)M_TOT * K_TOT * 2;
    const size_t offQKV = offWb  + (size_t)3 * H_ * H_ * 2;
    const size_t offPm  = offQKV + (size_t)M_TOT * N_TOT * 2;
    const size_t offPl  = offPm  + (size_t)B_ * NH_ * NCH * 4;
    const size_t offPo  = offPl  + (size_t)B_ * NH_ * NCH * 4;

    unsigned short* Xb  = (unsigned short*)(ws + offXb);
    unsigned short* Wb  = (unsigned short*)(ws + offWb);
    unsigned short* QKV = (unsigned short*)(ws + offQKV);
    float* Pm = (float*)(ws + offPm);
    float* Pl = (float*)(ws + offPl);
    float* Po = (float*)(ws + offPo);

    const int total8 = M_TOT * K_TOT / 8 + 3 * H_ * H_ / 8;   // 2490368, /256 exact
    hipLaunchKernelGGL(cvt_all, dim3(total8 / 256), dim3(256), 0, stream,
                       hs, Wq, Wk, Wv, Xb, Wb);
    hipLaunchKernelGGL(gemm_qkv, dim3(N_TOT / 128, M_TOT / 128), dim3(256), 0, stream,
                       Xb, Wb, bq, bk, bv, QKV);
    hipLaunchKernelGGL(gattn_part, dim3(B_ * NH_, NCH), dim3(256), 0, stream, QKV, mask, Pm, Pl, Po);
    hipLaunchKernelGGL(lattn, dim3(B_ * NH_, 129), dim3(256), 0, stream, QKV, out, lat, Pm, Pl, Po);
}